// Round 3
// baseline (166.144 us; speedup 1.0000x reference)
//
#include <hip/hip_runtime.h>

#define Bb 4
#define Qn 256
#define Kn 1024
#define Hn 128
#define QT 2  // q-rows per fused block

// qp/kp are pre-scaled by 2*log2(e) so exp2(qp'+kp') = e^{2(qp+kp)}.
constexpr float SCALE = 2.88539008177792681f;  // 2*log2(e)
constexpr float LOG2E = 1.44269504088896341f;

#if __has_builtin(__builtin_amdgcn_exp2f)
#define EXP2F(x) __builtin_amdgcn_exp2f(x)
#else
#define EXP2F(x) exp2f(x)
#endif
#if __has_builtin(__builtin_amdgcn_rcpf)
#define RCPF(x) __builtin_amdgcn_rcpf(x)
#else
#define RCPF(x) (1.0f / (x))
#endif

// ---------------------------------------------------------------------------
// K1: fused projections. Blocks [0, Bb*Qn/4) project query->qp (row-major,
// scaled); blocks [Bb*Qn/4, +Bb*Kn/4) project key->kpT (transposed [b,h,k],
// scaled). Block = 128 threads (one per h), 4 rows staged in LDS.
// ---------------------------------------------------------------------------
__global__ __launch_bounds__(128) void proj_kernel(const float* __restrict__ query,
                                                   const float* __restrict__ key,
                                                   const float* __restrict__ Wq,
                                                   const float* __restrict__ Wk,
                                                   float* __restrict__ qp,
                                                   float* __restrict__ kpT) {
    __shared__ float4 xs[128];  // 4 rows x 32 float4
    const int tid = threadIdx.x;
    const bool isQ = blockIdx.x < (Bb * Qn / 4);
    const int r0 = (isQ ? blockIdx.x : blockIdx.x - Bb * Qn / 4) * 4;
    const float* x = isQ ? query : key;
    const float* W = isQ ? Wq : Wk;

    xs[tid] = ((const float4*)(x + (size_t)r0 * Hn))[tid];
    __syncthreads();
    const float4* W4 = (const float4*)W + (size_t)tid * (Hn / 4);
    float acc0 = 0.f, acc1 = 0.f, acc2 = 0.f, acc3 = 0.f;
#pragma unroll 8
    for (int d = 0; d < Hn / 4; ++d) {
        float4 w = W4[d];
        float4 a0 = xs[d];
        float4 a1 = xs[32 + d];
        float4 a2 = xs[64 + d];
        float4 a3 = xs[96 + d];
        acc0 = fmaf(w.x, a0.x, fmaf(w.y, a0.y, fmaf(w.z, a0.z, fmaf(w.w, a0.w, acc0))));
        acc1 = fmaf(w.x, a1.x, fmaf(w.y, a1.y, fmaf(w.z, a1.z, fmaf(w.w, a1.w, acc1))));
        acc2 = fmaf(w.x, a2.x, fmaf(w.y, a2.y, fmaf(w.z, a2.z, fmaf(w.w, a2.w, acc2))));
        acc3 = fmaf(w.x, a3.x, fmaf(w.y, a3.y, fmaf(w.z, a3.z, fmaf(w.w, a3.w, acc3))));
    }
    if (isQ) {
        qp[(size_t)(r0 + 0) * Hn + tid] = acc0 * SCALE;
        qp[(size_t)(r0 + 1) * Hn + tid] = acc1 * SCALE;
        qp[(size_t)(r0 + 2) * Hn + tid] = acc2 * SCALE;
        qp[(size_t)(r0 + 3) * Hn + tid] = acc3 * SCALE;
    } else {
        const int b = r0 / Kn;
        const int k0 = r0 % Kn;
        float4 res = make_float4(acc0 * SCALE, acc1 * SCALE, acc2 * SCALE, acc3 * SCALE);
        ((float4*)kpT)[(size_t)(b * Hn + tid) * (Kn / 4) + (k0 >> 2)] = res;
    }
}

// ---------------------------------------------------------------------------
// K2: fused score + softmax + context. One block = (b, QT=2 q-rows), 256 thr.
//   phase A: score[q][k] = V - 2*sum_h v[h]*rcp(1 + exp2(qp'+kp'))  -> LDS
//            (thread t covers 2q x 4k, k = 4t..4t+3, one float4 kpT load / h)
//   phase B: row softmax in LDS (128 threads per row, shfl + LDS reduce),
//            normalized weights -> LDS + global attn out
//   phase C: ctx[q][h] = sum_k w[q][k]*value[b,k,h] (thread = (q, h))
// mask skipped: -1e-9*(1-mask) perturbs weights by ~1e-12.
// ---------------------------------------------------------------------------
__global__ __launch_bounds__(256) void fused_attn_kernel(const float* __restrict__ qp,
                                                         const float* __restrict__ kpT,
                                                         const float* __restrict__ v,
                                                         const float* __restrict__ value,
                                                         float* __restrict__ attn,
                                                         float* __restrict__ ctx) {
    const int tid = threadIdx.x;
    const int q0 = blockIdx.x * QT;
    const int b = blockIdx.y;

    __shared__ __align__(16) float qs[Hn][4];  // {qp(q0), qp(q0+1), v[h], pad}
    __shared__ __align__(16) float sc[QT][Kn]; // scores, then weights
    __shared__ float red[8];                   // [0..3] max per wave, [4..7] sum

    if (tid < Hn) {
        qs[tid][0] = qp[((size_t)b * Qn + q0) * Hn + tid];
        qs[tid][1] = qp[((size_t)b * Qn + q0 + 1) * Hn + tid];
        qs[tid][2] = v[tid];
        qs[tid][3] = 0.f;
    }
    __syncthreads();

    // V = sum_h v[h]  (broadcast LDS reads, once per block)
    float V = 0.f;
#pragma unroll
    for (int h = 0; h < Hn; ++h) V += qs[h][2];

    // ---- phase A: scores ----
    const float4* kp4 = (const float4*)(kpT + (size_t)b * Hn * Kn) + tid;
    float a00 = 0.f, a01 = 0.f, a02 = 0.f, a03 = 0.f;
    float a10 = 0.f, a11 = 0.f, a12 = 0.f, a13 = 0.f;
#pragma unroll 4
    for (int h = 0; h < Hn; ++h) {
        float4 kv = kp4[(size_t)h * (Kn / 4)];
        float4 qv = *(const float4*)(&qs[h][0]);  // {q0, q1, vh, _}
        float e, r;
        e = EXP2F(qv.x + kv.x); r = RCPF(1.0f + e); a00 = fmaf(qv.z, r, a00);
        e = EXP2F(qv.x + kv.y); r = RCPF(1.0f + e); a01 = fmaf(qv.z, r, a01);
        e = EXP2F(qv.x + kv.z); r = RCPF(1.0f + e); a02 = fmaf(qv.z, r, a02);
        e = EXP2F(qv.x + kv.w); r = RCPF(1.0f + e); a03 = fmaf(qv.z, r, a03);
        e = EXP2F(qv.y + kv.x); r = RCPF(1.0f + e); a10 = fmaf(qv.z, r, a10);
        e = EXP2F(qv.y + kv.y); r = RCPF(1.0f + e); a11 = fmaf(qv.z, r, a11);
        e = EXP2F(qv.y + kv.z); r = RCPF(1.0f + e); a12 = fmaf(qv.z, r, a12);
        e = EXP2F(qv.y + kv.w); r = RCPF(1.0f + e); a13 = fmaf(qv.z, r, a13);
    }
    ((float4*)&sc[0][0])[tid] = make_float4(V - 2.f * a00, V - 2.f * a01,
                                            V - 2.f * a02, V - 2.f * a03);
    ((float4*)&sc[1][0])[tid] = make_float4(V - 2.f * a10, V - 2.f * a11,
                                            V - 2.f * a12, V - 2.f * a13);
    __syncthreads();

    // ---- phase B: softmax (row r = tid>>7, chunk c = tid&127, 8 elems) ----
    const int r = tid >> 7, c = tid & 127;
    const int wv = tid >> 6, lane = tid & 63;
    float4 s0 = ((const float4*)&sc[r][0])[c * 2];
    float4 s1 = ((const float4*)&sc[r][0])[c * 2 + 1];
    float m = fmaxf(fmaxf(fmaxf(s0.x, s0.y), fmaxf(s0.z, s0.w)),
                    fmaxf(fmaxf(s1.x, s1.y), fmaxf(s1.z, s1.w)));
#pragma unroll
    for (int off = 32; off; off >>= 1) m = fmaxf(m, __shfl_xor(m, off));
    if (lane == 0) red[wv] = m;
    __syncthreads();
    const float mrow = fmaxf(red[r * 2], red[r * 2 + 1]);

    float4 e0, e1;
    e0.x = EXP2F((s0.x - mrow) * LOG2E); e0.y = EXP2F((s0.y - mrow) * LOG2E);
    e0.z = EXP2F((s0.z - mrow) * LOG2E); e0.w = EXP2F((s0.w - mrow) * LOG2E);
    e1.x = EXP2F((s1.x - mrow) * LOG2E); e1.y = EXP2F((s1.y - mrow) * LOG2E);
    e1.z = EXP2F((s1.z - mrow) * LOG2E); e1.w = EXP2F((s1.w - mrow) * LOG2E);
    float s = ((e0.x + e0.y) + (e0.z + e0.w)) + ((e1.x + e1.y) + (e1.z + e1.w));
#pragma unroll
    for (int off = 32; off; off >>= 1) s += __shfl_xor(s, off);
    if (lane == 0) red[4 + wv] = s;
    __syncthreads();
    const float inv = RCPF(red[4 + r * 2] + red[4 + r * 2 + 1]);

    float4 w0 = make_float4(e0.x * inv, e0.y * inv, e0.z * inv, e0.w * inv);
    float4 w1 = make_float4(e1.x * inv, e1.y * inv, e1.z * inv, e1.w * inv);
    ((float4*)&sc[r][0])[c * 2] = w0;
    ((float4*)&sc[r][0])[c * 2 + 1] = w1;
    float4* arow = (float4*)(attn + ((size_t)b * Qn + q0 + r) * Kn);
    arow[c * 2] = w0;
    arow[c * 2 + 1] = w1;
    __syncthreads();

    // ---- phase C: context ----
    const int hq = tid & 127, qq = tid >> 7;
    const float* vb = value + (size_t)b * Kn * Hn + hq;
    float acc = 0.f;
#pragma unroll 8
    for (int k = 0; k < Kn; ++k) acc = fmaf(sc[qq][k], vb[(size_t)k * Hn], acc);
    ctx[((size_t)b * Qn + q0 + qq) * Hn + hq] = acc;
}

// ---------------------------------------------------------------------------
extern "C" void kernel_launch(void* const* d_in, const int* in_sizes, int n_in,
                              void* d_out, int out_size, void* d_ws, size_t ws_size,
                              hipStream_t stream) {
    const float* query = (const float*)d_in[0];  // (4,256,128)
    const float* key = (const float*)d_in[1];    // (4,1024,128)
    const float* value = (const float*)d_in[2];  // (4,1024,128)
    // d_in[3] = mask: unused (NEG_MASK_SCALE = -1e-9 -> effect ~1e-12)
    const float* Wq = (const float*)d_in[4];
    const float* Wk = (const float*)d_in[5];
    const float* v = (const float*)d_in[6];

    float* out = (float*)d_out;
    float* attn = out;                        // B*Q*K floats
    float* ctx = out + (size_t)Bb * Qn * Kn;  // B*Q*H floats

    float* ws = (float*)d_ws;
    float* qp = ws;            // 131072 floats (scaled)
    float* kpT = ws + 131072;  // 524288 floats (scaled, [b,h,k])

    proj_kernel<<<dim3(Bb * Qn / 4 + Bb * Kn / 4), dim3(128), 0, stream>>>(
        query, key, Wq, Wk, qp, kpT);
    fused_attn_kernel<<<dim3(Qn / QT, Bb), dim3(256), 0, stream>>>(
        qp, kpT, v, value, attn, ctx);
}

// Round 4
// 118.040 us; speedup vs baseline: 1.4075x; 1.4075x over previous
//
#include <hip/hip_runtime.h>

#define Bb 4
#define Qn 256
#define Kn 1024
#define Hn 128

// Projections pre-scaled by 2*log2(e) and exponentiated: Eq=2^(s*qp), Ek=2^(s*kp)
// => e^{2(qp+kp)} = Eq*Ek, and tanh(qp+kp) = 1 - 2/(1+Eq*Ek).
constexpr float SCALE = 2.88539008177792681f;  // 2*log2(e)

#if __has_builtin(__builtin_amdgcn_exp2f)
#define EXP2F(x) __builtin_amdgcn_exp2f(x)
#else
#define EXP2F(x) exp2f(x)
#endif
#if __has_builtin(__builtin_amdgcn_rcpf)
#define RCPF(x) __builtin_amdgcn_rcpf(x)
#else
#define RCPF(x) (1.0f / (x))
#endif

// ---------------------------------------------------------------------------
// K1: fused projections. Blocks [0, Bb*Qn/4): query -> Eq (row-major).
// Blocks [Bb*Qn/4, +Bb*Kn/4): key -> EkT (transposed [b,h,k]).
// Both stored as exp2(SCALE * proj).
// ---------------------------------------------------------------------------
__global__ __launch_bounds__(128) void proj_kernel(const float* __restrict__ query,
                                                   const float* __restrict__ key,
                                                   const float* __restrict__ Wq,
                                                   const float* __restrict__ Wk,
                                                   float* __restrict__ eq,
                                                   float* __restrict__ ekT) {
    __shared__ float4 xs[128];  // 4 rows x 32 float4
    const int tid = threadIdx.x;
    const bool isQ = blockIdx.x < (Bb * Qn / 4);
    const int r0 = (isQ ? blockIdx.x : blockIdx.x - Bb * Qn / 4) * 4;
    const float* x = isQ ? query : key;
    const float* W = isQ ? Wq : Wk;

    xs[tid] = ((const float4*)(x + (size_t)r0 * Hn))[tid];
    __syncthreads();
    const float4* W4 = (const float4*)W + (size_t)tid * (Hn / 4);
    float acc0 = 0.f, acc1 = 0.f, acc2 = 0.f, acc3 = 0.f;
#pragma unroll 8
    for (int d = 0; d < Hn / 4; ++d) {
        float4 w = W4[d];
        float4 a0 = xs[d];
        float4 a1 = xs[32 + d];
        float4 a2 = xs[64 + d];
        float4 a3 = xs[96 + d];
        acc0 = fmaf(w.x, a0.x, fmaf(w.y, a0.y, fmaf(w.z, a0.z, fmaf(w.w, a0.w, acc0))));
        acc1 = fmaf(w.x, a1.x, fmaf(w.y, a1.y, fmaf(w.z, a1.z, fmaf(w.w, a1.w, acc1))));
        acc2 = fmaf(w.x, a2.x, fmaf(w.y, a2.y, fmaf(w.z, a2.z, fmaf(w.w, a2.w, acc2))));
        acc3 = fmaf(w.x, a3.x, fmaf(w.y, a3.y, fmaf(w.z, a3.z, fmaf(w.w, a3.w, acc3))));
    }
    if (isQ) {
        eq[(size_t)(r0 + 0) * Hn + tid] = EXP2F(acc0 * SCALE);
        eq[(size_t)(r0 + 1) * Hn + tid] = EXP2F(acc1 * SCALE);
        eq[(size_t)(r0 + 2) * Hn + tid] = EXP2F(acc2 * SCALE);
        eq[(size_t)(r0 + 3) * Hn + tid] = EXP2F(acc3 * SCALE);
    } else {
        const int b = r0 / Kn;
        const int k0 = r0 % Kn;
        float4 res = make_float4(EXP2F(acc0 * SCALE), EXP2F(acc1 * SCALE),
                                 EXP2F(acc2 * SCALE), EXP2F(acc3 * SCALE));
        ((float4*)ekT)[(size_t)(b * Hn + tid) * (Kn / 4) + (k0 >> 2)] = res;
    }
}

// ---------------------------------------------------------------------------
// K2: fused score + softmax + context. Block = 512 thr, (b, 2 q-rows).
// grid 512 blocks -> 16 waves/CU.
//   A: a[q][k] = sum_h v[h] * rcp(fma(Eq,Ek,1))   (tanh dot, V-term dropped:
//      softmax is shift-invariant, V = sum v is constant per problem)
//   B: softmax via min-reduce of a: w = 2^((amin-a)*SCALE) / sum
//   C: ctx[q][h] = sum_k w[q][k]*value[b,k,h], split-k in-block + LDS reduce
// mask skipped: -1e-9*(1-mask) perturbs weights by ~1e-12.
// ---------------------------------------------------------------------------
__global__ __launch_bounds__(512) void fused_attn_kernel(const float* __restrict__ eq,
                                                         const float* __restrict__ ekT,
                                                         const float* __restrict__ v,
                                                         const float* __restrict__ value,
                                                         float* __restrict__ attn,
                                                         float* __restrict__ ctx) {
    const int tid = threadIdx.x;
    const int q0 = blockIdx.x * 2;
    const int b = blockIdx.y;

    __shared__ __align__(16) float2 qs[Hn][2];  // [h][qq] = {Eq, v[h]}
    __shared__ __align__(16) float sc[2][Kn];   // weights
    __shared__ float red[16];                   // [0..7] min/wave, [8..15] sum
    __shared__ float pl[2][Hn][2];              // ctx partials [q][h][khalf]

    if (tid < Hn) {
        float e0 = eq[((size_t)b * Qn + q0) * Hn + tid];
        float e1 = eq[((size_t)b * Qn + q0 + 1) * Hn + tid];
        float vh = v[tid];
        qs[tid][0] = make_float2(e0, vh);
        qs[tid][1] = make_float2(e1, vh);
    }
    __syncthreads();

    // ---- phase A: scores (thread = (qq = tid>>8, k-chunk t = tid&255)) ----
    const int qq = tid >> 8;
    const int t = tid & 255;
    const float4* kp4 = (const float4*)(ekT + (size_t)b * Hn * Kn) + t;
    float a0 = 0.f, a1 = 0.f, a2 = 0.f, a3 = 0.f;
#pragma unroll 4
    for (int h = 0; h < Hn; ++h) {
        float4 kv = kp4[(size_t)h * (Kn / 4)];
        float2 qv = qs[h][qq];  // {Eq, vh}
        float r;
        r = RCPF(fmaf(qv.x, kv.x, 1.0f)); a0 = fmaf(qv.y, r, a0);
        r = RCPF(fmaf(qv.x, kv.y, 1.0f)); a1 = fmaf(qv.y, r, a1);
        r = RCPF(fmaf(qv.x, kv.z, 1.0f)); a2 = fmaf(qv.y, r, a2);
        r = RCPF(fmaf(qv.x, kv.w, 1.0f)); a3 = fmaf(qv.y, r, a3);
    }

    // ---- phase B: softmax. score = V - 2a -> shift-invariant: min-reduce a.
    const int lane = tid & 63, wv = tid >> 6;
    float mn = fminf(fminf(a0, a1), fminf(a2, a3));
#pragma unroll
    for (int off = 32; off; off >>= 1) mn = fminf(mn, __shfl_xor(mn, off));
    if (lane == 0) red[wv] = mn;
    __syncthreads();
    mn = fminf(fminf(red[qq * 4], red[qq * 4 + 1]),
               fminf(red[qq * 4 + 2], red[qq * 4 + 3]));

    float e0 = EXP2F((mn - a0) * SCALE);
    float e1 = EXP2F((mn - a1) * SCALE);
    float e2 = EXP2F((mn - a2) * SCALE);
    float e3 = EXP2F((mn - a3) * SCALE);
    float s = (e0 + e1) + (e2 + e3);
#pragma unroll
    for (int off = 32; off; off >>= 1) s += __shfl_xor(s, off);
    if (lane == 0) red[8 + wv] = s;
    __syncthreads();
    s = (red[8 + qq * 4] + red[8 + qq * 4 + 1]) +
        (red[8 + qq * 4 + 2] + red[8 + qq * 4 + 3]);
    const float inv = RCPF(s);

    float4 w4 = make_float4(e0 * inv, e1 * inv, e2 * inv, e3 * inv);
    ((float4*)&sc[qq][0])[t] = w4;
    ((float4*)(attn + ((size_t)b * Qn + q0 + qq) * Kn))[t] = w4;
    __syncthreads();

    // ---- phase C: context (thread = (kh = tid>>8, q2 = (tid>>7)&1, hq)) ----
    const int hq = tid & 127;
    const int q2 = (tid >> 7) & 1;
    const int kh = tid >> 8;
    const float* vb = value + ((size_t)b * Kn + kh * (Kn / 2)) * Hn + hq;
    const float4* wrow = (const float4*)&sc[q2][kh * (Kn / 2)];
    float acc = 0.f;
#pragma unroll 4
    for (int k4 = 0; k4 < Kn / 8; ++k4) {
        float4 wv4 = wrow[k4];
        acc = fmaf(wv4.x, vb[(size_t)(4 * k4 + 0) * Hn], acc);
        acc = fmaf(wv4.y, vb[(size_t)(4 * k4 + 1) * Hn], acc);
        acc = fmaf(wv4.z, vb[(size_t)(4 * k4 + 2) * Hn], acc);
        acc = fmaf(wv4.w, vb[(size_t)(4 * k4 + 3) * Hn], acc);
    }
    pl[q2][hq][kh] = acc;
    __syncthreads();
    if (tid < 256) {
        const int qo = tid >> 7, ho = tid & 127;
        ctx[((size_t)b * Qn + q0 + qo) * Hn + ho] = pl[qo][ho][0] + pl[qo][ho][1];
    }
}

// ---------------------------------------------------------------------------
extern "C" void kernel_launch(void* const* d_in, const int* in_sizes, int n_in,
                              void* d_out, int out_size, void* d_ws, size_t ws_size,
                              hipStream_t stream) {
    const float* query = (const float*)d_in[0];  // (4,256,128)
    const float* key = (const float*)d_in[1];    // (4,1024,128)
    const float* value = (const float*)d_in[2];  // (4,1024,128)
    // d_in[3] = mask: unused (NEG_MASK_SCALE = -1e-9 -> effect ~1e-12)
    const float* Wq = (const float*)d_in[4];
    const float* Wk = (const float*)d_in[5];
    const float* v = (const float*)d_in[6];

    float* out = (float*)d_out;
    float* attn = out;                        // B*Q*K floats
    float* ctx = out + (size_t)Bb * Qn * Kn;  // B*Q*H floats

    float* ws = (float*)d_ws;
    float* eq = ws;             // 131072 floats: exp2(SCALE*qp)
    float* ekT = ws + 131072;   // 524288 floats: exp2(SCALE*kp), [b,h,k]

    proj_kernel<<<dim3(Bb * Qn / 4 + Bb * Kn / 4), dim3(128), 0, stream>>>(
        query, key, Wq, Wk, eq, ekT);
    fused_attn_kernel<<<dim3(Qn / 2, Bb), dim3(512), 0, stream>>>(
        eq, ekT, v, value, attn, ctx);
}